// Round 6
// baseline (759.953 us; speedup 1.0000x reference)
//
#include <hip/hip_runtime.h>
#include <math.h>

#define NSITE 100
#define NOCC  50
#define DIM   128
#define KDET  4

// readlane of a double via two 32-bit readlanes (p is wave-uniform)
__device__ __forceinline__ double readlane_d(double v, int p) {
  int lo = __builtin_amdgcn_readlane(__double2loint(v), p);
  int hi = __builtin_amdgcn_readlane(__double2hiint(v), p);
  return __hiloint2double(hi, lo);
}

// ---- Compile-time-indexed GEMM helpers ------------------------------------
// LLVM's first SROA pass runs BEFORE loop unrolling: any source-level
// variable index (even in a '#pragma unroll' loop) leaves a dynamic GEP and
// the whole alloca stays in scratch forever (R2-R5: VGPR=64-68, ~900-757us).
// Every acc[]/row[] access must therefore be constant-indexed IN THE SOURCE.
template <int JJ>
struct GemmCol {
  static __device__ __forceinline__ void init(float (&acc)[NOCC],
                                              const float* bb) {
    acc[JJ] = bb[JJ];
    GemmCol<JJ + 1>::init(acc, bb);
  }
  static __device__ __forceinline__ void step(float (&acc)[NOCC],
      const float4* W4, int d4, float a0, float a1, float a2, float a3) {
    float4 w = W4[JJ * (DIM / 4) + d4];
    float s = fmaf(a0, w.x, acc[JJ]);
    s = fmaf(a1, w.y, s);
    s = fmaf(a2, w.z, s);
    acc[JJ] = fmaf(a3, w.w, s);
    GemmCol<JJ + 1>::step(acc, W4, d4, a0, a1, a2, a3);
  }
  static __device__ __forceinline__ void convert(const float (&acc)[NOCC],
      double (&row)[NOCC], bool act) {
    row[JJ] = act ? (double)acc[JJ] : 0.0;
    GemmCol<JJ + 1>::convert(acc, row, act);
  }
};
template <>
struct GemmCol<NOCC> {
  static __device__ __forceinline__ void init(float (&)[NOCC], const float*) {}
  static __device__ __forceinline__ void step(float (&)[NOCC], const float4*,
                                              int, float, float, float, float) {}
  static __device__ __forceinline__ void convert(const float (&)[NOCC],
                                                 double (&)[NOCC], bool) {}
};

// One LU pivot step with COMPILE-TIME step index J (same SROA reasoning).
template <int J>
struct LUStep {
  static __device__ __forceinline__ void run(double (&row)[NOCC], int lane,
      unsigned& alive, double& mant_prod, int& esum, int& neg, int& mystep) {
    // pivot key: |row[J]| high-word (monotonic for abs), low 6 bits = lane
    unsigned hi  = (unsigned)__double2hiint(fabs(row[J]));
    unsigned key = alive ? ((hi & ~63u) | (unsigned)lane) : 0u;
    #pragma unroll
    for (int m = 32; m >= 1; m >>= 1) {
      unsigned o = (unsigned)__shfl_xor((int)key, m, 64);
      key = key > o ? key : o;
    }
    const int p = __builtin_amdgcn_readfirstlane((int)(key & 63u));
    const double piv = readlane_d(row[J], p);

    // piv = sign * mant * 2^(e-1023): accumulate exponent, sign, mantissa
    const unsigned phiw = (unsigned)__double2hiint(piv);
    esum += (int)((phiw >> 20) & 0x7ffu) - 1023;
    neg  += (int)(phiw >> 31);
    mant_prod *= __hiloint2double((int)((phiw & 0x000FFFFFu) | 0x3FF00000u),
                                  __double2loint(piv));

    if (lane == p) mystep = J;
    alive &= (lane != p) ? 1u : 0u;
    const double rp   = (piv != 0.0) ? 1.0 / piv : 0.0;
    const double mult = alive ? row[J] * rp : 0.0;
    #pragma unroll
    for (int cc = J + 1; cc < NOCC; ++cc) {   // compile-time bounds
      const double pc = readlane_d(row[cc], p);
      row[cc] = fma(-mult, pc, row[cc]);
    }
    LUStep<J + 1>::run(row, lane, alive, mant_prod, esum, neg, mystep);
  }
};
template <>
struct LUStep<NOCC> {
  static __device__ __forceinline__ void run(double (&)[NOCC], int,
      unsigned&, double&, int&, int&, int&) {}
};

// One block per (batch, spin). Wave w handles determinant k=w.
// Lane r owns row r of phi entirely in registers (r < 50).
__global__ __launch_bounds__(256, 2) void det_kernel(
    const int*   __restrict__ configs,   // (B,100) int32
    const float* __restrict__ tok,       // (4,128)
    const float* __restrict__ pos,       // (144,128)
    const float* __restrict__ W,         // (400,128)
    const float* __restrict__ bvec,      // (400,)
    double*      __restrict__ dets)      // (B,2,4,2)  {logdet, sign}
{
  const int b    = blockIdx.x;
  const int spin = blockIdx.y;

  __shared__ int cfg[NSITE];
  __shared__ int idx[NOCC];
  __shared__ int occl[NOCC];
  __shared__ int filll[NOCC];
  __shared__ int perm[4][NOCC];

  const int tid = threadIdx.x;
  if (tid < NSITE) cfg[tid] = configs[(size_t)b * NSITE + tid];
  __syncthreads();

  // Occupied-index list per reference argsort semantics: all occupied sites
  // (ascending, capped 50) + smallest unoccupied fill, merged sorted.
  if (tid == 0) {
    int no = 0, nf = 0;
    for (int n = 0; n < NSITE; ++n) {
      int c = cfg[n];
      bool occ = (spin == 0) ? (c == 1 || c == 3) : (c == 2 || c == 3);
      if (occ) { if (no < NOCC) occl[no++]  = n; }
      else     { if (nf < NOCC) filll[nf++] = n; }
    }
    int need = NOCC - no; if (need < 0) need = 0;
    int i = 0, j = 0;
    for (int k = 0; k < NOCC; ++k) {
      bool takeocc = (i < no) && (j >= need || occl[i] < filll[j]);
      idx[k] = takeocc ? occl[i++] : filll[j++];
    }
  }
  __syncthreads();

  const int lane = tid & 63;
  const int wave = tid >> 6;
  const int wave_u  = __builtin_amdgcn_readfirstlane(wave);
  const int colbase = spin * 200 + wave_u * 50;          // uniform
  const float* Wb = W    + (size_t)colbase * DIM;        // uniform base
  const float* bb = bvec + colbase;

  const int  r   = lane;
  const bool act = (r < NOCC);
  const int  site = idx[act ? r : 0];
  const int  c    = cfg[site];
  const float4* tok4 = (const float4*)(tok + (size_t)c    * DIM);
  const float4* pos4 = (const float4*)(pos + (size_t)site * DIM);

  // ---- GEMM (fp32): row r of phi_k = h . W[colbase+j] + b ----
  float acc[NOCC];
  GemmCol<0>::init(acc, bb);
  const float4* W4 = (const float4*)Wb;
  for (int d4 = 0; d4 < DIM / 4; ++d4) {
    float4 t = tok4[d4], p = pos4[d4];
    GemmCol<0>::step(acc, W4, d4, t.x + p.x, t.y + p.y, t.z + p.z, t.w + p.w);
  }

  double row[NOCC];
  GemmCol<0>::convert(acc, row, act);

  // ---- LU (fp64), register-resident, fully unrolled via templates ----
  double mant_prod = 1.0;
  int    esum = 0, neg = 0, mystep = -1;
  unsigned alive = act ? 1u : 0u;
  LUStep<0>::run(row, lane, alive, mant_prod, esum, neg, mystep);

  double logdet = log(mant_prod) + (double)esum * 0.6931471805599453;

  // permutation parity: perm[step] = lane chosen at that step
  if (mystep >= 0) perm[wave][mystep] = lane;
  __syncthreads();
  int pj  = perm[wave][act ? lane : 0];
  int inv = 0;
  for (int i = 0; i < NOCC; ++i) {
    int pi = perm[wave][i];
    inv += (act && i < lane && pi > pj) ? 1 : 0;
  }
  #pragma unroll
  for (int m = 32; m >= 1; m >>= 1) inv += __shfl_xor(inv, m, 64);

  const int sgn = ((neg + inv) & 1) ? -1 : 1;
  if (lane == 0) {
    size_t o = (((size_t)b * 2 + spin) * KDET + wave) * 2;
    dets[o]     = logdet;
    dets[o + 1] = (double)sgn;
  }
}

// PLANAR complex64 output: out[0..B) = log_abs (real), out[B..2B) = phase (imag)
__global__ __launch_bounds__(256) void combine_kernel(
    const double* __restrict__ dets, float* __restrict__ out, int B)
{
  int b = blockIdx.x * blockDim.x + threadIdx.x;
  if (b >= B) return;
  const double* du = dets + ((size_t)b * 2 + 0) * KDET * 2;
  const double* dd = dets + ((size_t)b * 2 + 1) * KDET * 2;
  double t[KDET], s[KDET], m = -1e300;
  #pragma unroll
  for (int k = 0; k < KDET; ++k) {
    t[k] = du[2 * k] + dd[2 * k];
    s[k] = du[2 * k + 1] * dd[2 * k + 1];
    if (t[k] > m) m = t[k];
  }
  double sum = 0.0;
  #pragma unroll
  for (int k = 0; k < KDET; ++k) {
    if (t[k] > -1e290) sum += s[k] * exp(t[k] - m);
  }
  double p  = (m > -1e290) ? exp(m) * fabs(sum) : 0.0;
  double la = log(p + 1e-30);                    // reproduce ref clamp exactly
  float phase = (sum >= 0.0) ? 0.0f : 3.14159265358979f;
  out[b]     = (float)la;
  out[B + b] = phase;
}

extern "C" void kernel_launch(void* const* d_in, const int* in_sizes, int n_in,
                              void* d_out, int out_size, void* d_ws, size_t ws_size,
                              hipStream_t stream) {
  const int*   configs = (const int*)  d_in[0];
  const float* tok     = (const float*)d_in[1];
  const float* pos     = (const float*)d_in[2];
  const float* W       = (const float*)d_in[3];
  const float* bv      = (const float*)d_in[4];
  double* dets = (double*)d_ws;            // needs B*2*4*2*8 = 256 KB
  const int B = in_sizes[0] / NSITE;

  dim3 grid(B, 2);
  det_kernel<<<grid, 256, 0, stream>>>(configs, tok, pos, W, bv, dets);
  combine_kernel<<<(B + 255) / 256, 256, 0, stream>>>(dets, (float*)d_out, B);
}

// Round 7
// 757.847 us; speedup vs baseline: 1.0028x; 1.0028x over previous
//
#include <hip/hip_runtime.h>
#include <math.h>

#define NSITE 100
#define NOCC  50
#define DIM   128
#define KDET  4

// readlane of a double via two 32-bit readlanes (p is wave-uniform)
__device__ __forceinline__ double readlane_d(double v, int p) {
  int lo = __builtin_amdgcn_readlane(__double2loint(v), p);
  int hi = __builtin_amdgcn_readlane(__double2hiint(v), p);
  return __hiloint2double(hi, lo);
}

// butterfly max across 64 lanes (scalar arg/ret only -> no alloca involved)
__device__ __forceinline__ unsigned maxkey64(unsigned key) {
  #pragma unroll
  for (int m = 32; m >= 1; m >>= 1) {
    unsigned o = (unsigned)__shfl_xor((int)key, m, 64);
    key = key > o ? key : o;
  }
  return key;
}

// ---------------------------------------------------------------------------
// R2-R6 lesson: every formulation that kept phi-row in a C array ended with
// the alloca in scratch (VGPR pinned at 64-68; dynamic GEPs in R2/R3/R5,
// by-reference escape through the 50-deep "forceinline" recursion in R4/R6).
// Fix: NO ARRAYS AT ALL. 50 named scalars via preprocessor repetition.
// REPA/REPB are identical; two copies needed because a macro cannot expand
// recursively (LU steps expand REPA, their inner updates expand REPB).
// ---------------------------------------------------------------------------
#define REPA(X) X(0) X(1) X(2) X(3) X(4) X(5) X(6) X(7) X(8) X(9) \
  X(10) X(11) X(12) X(13) X(14) X(15) X(16) X(17) X(18) X(19) \
  X(20) X(21) X(22) X(23) X(24) X(25) X(26) X(27) X(28) X(29) \
  X(30) X(31) X(32) X(33) X(34) X(35) X(36) X(37) X(38) X(39) \
  X(40) X(41) X(42) X(43) X(44) X(45) X(46) X(47) X(48) X(49)
#define REPB(X) X(0) X(1) X(2) X(3) X(4) X(5) X(6) X(7) X(8) X(9) \
  X(10) X(11) X(12) X(13) X(14) X(15) X(16) X(17) X(18) X(19) \
  X(20) X(21) X(22) X(23) X(24) X(25) X(26) X(27) X(28) X(29) \
  X(30) X(31) X(32) X(33) X(34) X(35) X(36) X(37) X(38) X(39) \
  X(40) X(41) X(42) X(43) X(44) X(45) X(46) X(47) X(48) X(49)

// One block per (batch, spin). Wave w handles determinant k=w.
// Lane r owns row r of phi entirely in named registers (r < 50).
__global__ __launch_bounds__(256, 2) void det_kernel(
    const int*   __restrict__ configs,   // (B,100) int32
    const float* __restrict__ tok,       // (4,128)
    const float* __restrict__ pos,       // (144,128)
    const float* __restrict__ W,         // (400,128)
    const float* __restrict__ bvec,      // (400,)
    double*      __restrict__ dets)      // (B,2,4,2)  {logdet, sign}
{
  const int b    = blockIdx.x;
  const int spin = blockIdx.y;

  __shared__ int cfg[NSITE];
  __shared__ int idx[NOCC];
  __shared__ int occl[NOCC];
  __shared__ int filll[NOCC];
  __shared__ int perm[4][NOCC];

  const int tid = threadIdx.x;
  if (tid < NSITE) cfg[tid] = configs[(size_t)b * NSITE + tid];
  __syncthreads();

  // Occupied-index list per reference argsort semantics: all occupied sites
  // (ascending, capped 50) + smallest unoccupied fill, merged sorted.
  if (tid == 0) {
    int no = 0, nf = 0;
    for (int n = 0; n < NSITE; ++n) {
      int c = cfg[n];
      bool occ = (spin == 0) ? (c == 1 || c == 3) : (c == 2 || c == 3);
      if (occ) { if (no < NOCC) occl[no++]  = n; }
      else     { if (nf < NOCC) filll[nf++] = n; }
    }
    int need = NOCC - no; if (need < 0) need = 0;
    int i = 0, j = 0;
    for (int k = 0; k < NOCC; ++k) {
      bool takeocc = (i < no) && (j >= need || occl[i] < filll[j]);
      idx[k] = takeocc ? occl[i++] : filll[j++];
    }
  }
  __syncthreads();

  const int lane = tid & 63;
  const int wave = tid >> 6;
  const int wave_u  = __builtin_amdgcn_readfirstlane(wave);
  const int colbase = spin * 200 + wave_u * 50;          // uniform
  const float* Wb = W    + (size_t)colbase * DIM;        // uniform base
  const float* bb = bvec + colbase;

  const bool act  = (lane < NOCC);
  const int  site = idx[act ? lane : 0];
  const int  cc0  = cfg[site];
  const float4* tok4 = (const float4*)(tok + (size_t)cc0  * DIM);
  const float4* pos4 = (const float4*)(pos + (size_t)site * DIM);
  const float4* W4   = (const float4*)Wb;

  // ---- GEMM (fp32): q0..q49 = h . W[colbase + 0..49] + b ----
  #define DECLQ(i) float q##i = bb[i];
  REPB(DECLQ)
  #undef DECLQ

  for (int d4 = 0; d4 < DIM / 4; ++d4) {
    float4 t = tok4[d4], pv = pos4[d4];
    const float h0 = t.x + pv.x, h1 = t.y + pv.y;
    const float h2 = t.z + pv.z, h3 = t.w + pv.w;
    #define GSTEP(i) { float4 w = W4[(i) * (DIM / 4) + d4]; \
      q##i = fmaf(h3, w.w, fmaf(h2, w.z, fmaf(h1, w.y, fmaf(h0, w.x, q##i)))); }
    REPB(GSTEP)
    #undef GSTEP
  }

  // ---- convert to fp64 rows x0..x49 (inactive lanes -> 0) ----
  #define DECLX(i) double x##i = act ? (double)q##i : 0.0;
  REPB(DECLX)
  #undef DECLX

  // ---- LU (fp64) with implicit partial pivoting, all state in registers ---
  double mant_prod = 1.0;
  int    esum = 0, neg = 0, mystep = -1;
  unsigned alive = act ? 1u : 0u;

  #define UPD(CC) if ((CC) > cJ) { \
      x##CC = fma(-mult, readlane_d(x##CC, p), x##CC); }
  #define LUS(J) { \
    unsigned hiw = (unsigned)__double2hiint(fabs(x##J)); \
    unsigned key = alive ? ((hiw & ~63u) | (unsigned)lane) : 0u; \
    key = maxkey64(key); \
    const int p = __builtin_amdgcn_readfirstlane((int)(key & 63u)); \
    const double piv = readlane_d(x##J, p); \
    const unsigned phiw = (unsigned)__double2hiint(piv); \
    esum += (int)((phiw >> 20) & 0x7ffu) - 1023; \
    neg  += (int)(phiw >> 31); \
    mant_prod *= __hiloint2double((int)((phiw & 0x000FFFFFu) | 0x3FF00000u), \
                                  __double2loint(piv)); \
    if (lane == p) mystep = (J); \
    alive &= (lane != p) ? 1u : 0u; \
    const double rp = (piv != 0.0) ? 1.0 / piv : 0.0; \
    const double mult = alive ? x##J * rp : 0.0; \
    const int cJ = (J); \
    REPB(UPD) \
  }
  REPA(LUS)
  #undef LUS
  #undef UPD

  double logdet = log(mant_prod) + (double)esum * 0.6931471805599453;

  // permutation parity: perm[step] = lane chosen at that step (LDS, fine)
  if (mystep >= 0) perm[wave][mystep] = lane;
  __syncthreads();
  int pj  = perm[wave][act ? lane : 0];
  int inv = 0;
  for (int i = 0; i < NOCC; ++i) {
    int pi = perm[wave][i];
    inv += (act && i < lane && pi > pj) ? 1 : 0;
  }
  #pragma unroll
  for (int m = 32; m >= 1; m >>= 1) inv += __shfl_xor(inv, m, 64);

  const int sgn = ((neg + inv) & 1) ? -1 : 1;
  if (lane == 0) {
    size_t o = (((size_t)b * 2 + spin) * KDET + wave) * 2;
    dets[o]     = logdet;
    dets[o + 1] = (double)sgn;
  }
}

// PLANAR complex64 output: out[0..B) = log_abs (real), out[B..2B) = phase (imag)
__global__ __launch_bounds__(256) void combine_kernel(
    const double* __restrict__ dets, float* __restrict__ out, int B)
{
  int b = blockIdx.x * blockDim.x + threadIdx.x;
  if (b >= B) return;
  const double* du = dets + ((size_t)b * 2 + 0) * KDET * 2;
  const double* dd = dets + ((size_t)b * 2 + 1) * KDET * 2;
  double t[KDET], s[KDET], m = -1e300;
  #pragma unroll
  for (int k = 0; k < KDET; ++k) {
    t[k] = du[2 * k] + dd[2 * k];
    s[k] = du[2 * k + 1] * dd[2 * k + 1];
    if (t[k] > m) m = t[k];
  }
  double sum = 0.0;
  #pragma unroll
  for (int k = 0; k < KDET; ++k) {
    if (t[k] > -1e290) sum += s[k] * exp(t[k] - m);
  }
  double p  = (m > -1e290) ? exp(m) * fabs(sum) : 0.0;
  double la = log(p + 1e-30);                    // reproduce ref clamp exactly
  float phase = (sum >= 0.0) ? 0.0f : 3.14159265358979f;
  out[b]     = (float)la;
  out[B + b] = phase;
}

extern "C" void kernel_launch(void* const* d_in, const int* in_sizes, int n_in,
                              void* d_out, int out_size, void* d_ws, size_t ws_size,
                              hipStream_t stream) {
  const int*   configs = (const int*)  d_in[0];
  const float* tok     = (const float*)d_in[1];
  const float* pos     = (const float*)d_in[2];
  const float* W       = (const float*)d_in[3];
  const float* bv      = (const float*)d_in[4];
  double* dets = (double*)d_ws;            // needs B*2*4*2*8 = 256 KB
  const int B = in_sizes[0] / NSITE;

  dim3 grid(B, 2);
  det_kernel<<<grid, 256, 0, stream>>>(configs, tok, pos, W, bv, dets);
  combine_kernel<<<(B + 255) / 256, 256, 0, stream>>>(dets, (float*)d_out, B);
}